// Round 5
// baseline (369.426 us; speedup 1.0000x reference)
//
#include <hip/hip_runtime.h>
#include <math.h>

// Problem: N=8, C=1, H=W=512 fp32. 16 images (8 sigmoid + 8 target) skeletonized.
#define IMG   512
#define NSAMP 8
#define NIMG  16
#define PS    (IMG * IMG)

#define NBANDS 16
#define BH     (IMG / NBANDS)   // 32

__device__ __forceinline__ float sigm(float x) { return 1.0f / (1.0f + expf(-x)); }

// ---- cross-lane shift by 1 at VALU rate (DPP). Stencils are L/R symmetric,
// so shift direction need not be disambiguated. Shifted-in lanes -> 0; garbage
// contained in the (C+1)-lane column halo.
__device__ __forceinline__ float dpp_a(float x) {
#if __has_builtin(__builtin_amdgcn_update_dpp)
    return __int_as_float(__builtin_amdgcn_update_dpp(0, __float_as_int(x),
                                                      0x130, 0xF, 0xF, true)); // WAVE_SHL1
#else
    return __shfl_down(x, 1, 64);
#endif
}
__device__ __forceinline__ float dpp_b(float x) {
#if __has_builtin(__builtin_amdgcn_update_dpp)
    return __int_as_float(__builtin_amdgcn_update_dpp(0, __float_as_int(x),
                                                      0x138, 0xF, 0xF, true)); // WAVE_SHR1
#else
    return __shfl_up(x, 1, 64);
#endif
}

// ---- prep: X[0:n]=sigmoid(logits), X[n:2n]=target (S untouched: first fused
// launch is INIT and neither reads nor needs zeroed S) ----
__global__ __launch_bounds__(256) void prep_kernel(const float4* __restrict__ lg,
                                                   const float4* __restrict__ tg,
                                                   float4* __restrict__ X, int n4)
{
    int i = blockIdx.x * 256 + threadIdx.x;
    if (i < n4) {
        float4 L = lg[i];
        X[i]      = make_float4(sigm(L.x), sigm(L.y), sigm(L.z), sigm(L.w));
        X[i + n4] = tg[i];
    }
}

// ---- register line-pipeline, 2 rows per step, C fused levels, no LDS ----
// Level l at step t consumes x_l rows t-l-2..t-l+1 (A,B,Cin,Din) and produces
//   e1 = x_{l+1}[t-l-1], e2 = x_{l+1}[t-l]  (cross-erode, OOB=+inf)
//   hm1/hm2 = rowmax3(e) at those rows (OOB=-inf)
//   dil1 (row t-l-2) = max(HMA,HMB,hm1); dil2 (row t-l-1) = max(HMB,hm1,hm2)
//   delta1 = relu(A-dil1); delta2 = relu(B-dil2); skel updates rows t-l-2,t-l-1.
// Skel chain: level l+1's inputs are (CARRY[l+1] = level l's skb_out of the
// previous step) and (level l's ska_out of the current step).
template<int C, bool ER, bool EC, bool INIT>
__device__ __forceinline__ void pipe_run(const float* __restrict__ xg,
                                         float* __restrict__ xo,
                                         float* __restrict__ Sg,
                                         int R0, int gcol, bool colOK, bool owned)
{
    const float INF = __builtin_inff();
    float A[C], B[C], HMA[C], HMB[C], CARRY[C];     // CARRY[0] unused
    #pragma unroll
    for (int l = 0; l < C; ++l) {
        A[l] = INF; B[l] = INF; HMA[l] = -INF; HMB[l] = -INF; CARRY[l] = 0.f;
    }
    const int t0 = R0 - C - 1;
    constexpr int NSTEPS = (BH + 2 * C + 2) / 2;

    auto xld = [&](int r) -> float {
        if (ER || EC) {
            bool ok = (!ER || (unsigned)r < (unsigned)IMG) && (!EC || colOK);
            float v = INF;
            if (ok) v = xg[r * IMG + gcol];
            return v;
        }
        return xg[r * IMG + gcol];     // interior: provably in-bounds
    };
    auto sld = [&](int r) -> float {
        if (INIT) return 0.f;
        if (ER || EC) {
            bool ok = (!ER || (unsigned)r < (unsigned)IMG) && (!EC || colOK);
            float v = 0.f;
            if (ok) v = Sg[r * IMG + gcol];
            return v;
        }
        return Sg[r * IMG + gcol];
    };

    // one-step (2-row) software prefetch on both streams
    float Xc0 = xld(t0),     Xc1 = xld(t0 + 1);
    float Xn0 = xld(t0 + 2), Xn1 = xld(t0 + 3);
    float Sc0 = sld(t0 - 2), Sc1 = sld(t0 - 1);
    float Sn0 = sld(t0),     Sn1 = sld(t0 + 1);

    #pragma unroll 2
    for (int k = 0; k < NSTEPS; ++k) {
        const int t = t0 + 2 * k;
        float Cin = Xc0, Din = Xc1;
        float ska = Sc0, skb = Sc1;
        Xc0 = Xn0; Xc1 = Xn1; Xn0 = xld(t + 4); Xn1 = xld(t + 5);
        Sc0 = Sn0; Sc1 = Sn1; Sn0 = sld(t + 2); Sn1 = sld(t + 3);

        float sk_a = 0.f, sk_b = 0.f;

        #pragma unroll
        for (int l = 0; l < C; ++l) {
            float Acur = A[l], Bcur = B[l];
            // erode (cross): vertical min3 + horizontal via DPP on center row
            float v1 = fminf(fminf(Acur, Bcur), Cin);
            float v2 = fminf(fminf(Bcur, Cin), Din);
            float e1 = fminf(v1, fminf(dpp_a(Bcur), dpp_b(Bcur)));
            float e2 = fminf(v2, fminf(dpp_a(Cin), dpp_b(Cin)));
            if (ER) {   // wave-uniform row forcing
                e1 = ((unsigned)(t - l - 1) < (unsigned)IMG) ? e1 : INF;
                e2 = ((unsigned)(t - l)     < (unsigned)IMG) ? e2 : INF;
            }
            float xd1 = e1, xd2 = e2;
            if (EC) {   // per-lane column forcing
                xd1 = colOK ? e1 : -INF;  e1 = colOK ? e1 : INF;
                xd2 = colOK ? e2 : -INF;  e2 = colOK ? e2 : INF;
            }
            float hm1 = fmaxf(xd1, fmaxf(dpp_a(xd1), dpp_b(xd1)));
            float hm2 = fmaxf(xd2, fmaxf(dpp_a(xd2), dpp_b(xd2)));
            if (ER) {
                hm1 = ((unsigned)(t - l - 1) < (unsigned)IMG) ? hm1 : -INF;
                hm2 = ((unsigned)(t - l)     < (unsigned)IMG) ? hm2 : -INF;
            }
            float dil1 = fmaxf(fmaxf(HMA[l], HMB[l]), hm1);
            float dil2 = fmaxf(fmaxf(HMB[l], hm1), hm2);
            float d1 = fmaxf(Acur - dil1, 0.f);
            float d2 = fmaxf(Bcur - dil2, 0.f);
            float so_a = ska + fmaxf(d1 - ska * d1, 0.f);   // skel row t-l-2
            float so_b = skb + fmaxf(d2 - skb * d2, 0.f);   // skel row t-l-1
            // rotate windows (advance 2 rows)
            A[l] = Cin; B[l] = Din;
            HMA[l] = hm1; HMB[l] = hm2;
            // next level inputs
            Cin = e1; Din = e2;
            if (l + 1 < C) {
                float tmp = CARRY[l + 1];   // level l's skb_out of previous step
                CARRY[l + 1] = so_b;
                ska = tmp;                  // skel row t-(l+1)-2, updated thru l
                skb = so_a;                 // skel row t-(l+1)-1, updated thru l
            } else {
                sk_a = so_a; sk_b = so_b;
            }
        }

        // stores: skel rows t-C-1, t-C; x_C rows t-C, t-C+1 (band-guarded)
        if (owned) {
            int rs0 = t - C - 1, rs1 = t - C, rx1 = t - C + 1;
            if ((unsigned)(rs0 - R0) < BH) Sg[rs0 * IMG + gcol] = sk_a;
            if ((unsigned)(rs1 - R0) < BH) Sg[rs1 * IMG + gcol] = sk_b;
            if ((unsigned)(rs1 - R0) < BH) xo[rs1 * IMG + gcol] = Cin;
            if ((unsigned)(rx1 - R0) < BH) xo[rx1 * IMG + gcol] = Din;
        }
    }
}

template<int C, bool INIT>
__global__ __launch_bounds__(256) void fused_pipe(const float* __restrict__ xin,
                                                  float* __restrict__ xout,
                                                  float* __restrict__ S)
{
    constexpr int OW = 64 - 2 * (C + 1);                 // owned cols per wave
    constexpr int NSTRIP = (IMG + OW - 1) / OW;          // 10 (C=5), 11 (C=6)
    const int lane = threadIdx.x & 63;
    const int task = blockIdx.x * 4 + (threadIdx.x >> 6);
    const int strip = task % NSTRIP;
    const int rem = task / NSTRIP;
    const int band = rem % NBANDS;
    const int img = rem / NBANDS;
    const int R0 = band * BH;
    const int gcol = strip * OW - (C + 1) + lane;
    const bool colOK = (unsigned)gcol < (unsigned)IMG;
    const bool owned = (lane >= C + 1) && (lane < C + 1 + OW) && colOK;
    const float* xg = xin + (size_t)img * PS;
    float* xo = xout + (size_t)img * PS;
    float* Sg = S + (size_t)img * PS;
    const bool erow = (band == 0) || (band == NBANDS - 1);
    const bool ecol = (strip == 0) || (strip * OW - (C + 1) + 63 >= IMG);

    if (erow) {
        if (ecol) pipe_run<C, true , true , INIT>(xg, xo, Sg, R0, gcol, colOK, owned);
        else      pipe_run<C, true , false, INIT>(xg, xo, Sg, R0, gcol, colOK, owned);
    } else {
        if (ecol) pipe_run<C, false, true , INIT>(xg, xo, Sg, R0, gcol, colOK, owned);
        else      pipe_run<C, false, false, INIT>(xg, xo, Sg, R0, gcol, colOK, owned);
    }
}

// ---- reduction: per-block partials, no global atomics ----
__global__ __launch_bounds__(256) void reduce_kernel(const float* __restrict__ logits,
                                                     const float* __restrict__ target,
                                                     const float* __restrict__ S,
                                                     float* __restrict__ partial)
{
    const int sample = blockIdx.y;
    const size_t base = (size_t)sample * PS;
    const float4* p4  = (const float4*)(logits + base);
    const float4* t4  = (const float4*)(target + base);
    const float4* sp4 = (const float4*)(S + base);
    const float4* sl4 = (const float4*)(S + (size_t)NSAMP * PS + base);
    float v[7] = {0.f, 0.f, 0.f, 0.f, 0.f, 0.f, 0.f};
    const int n4 = PS / 4;
    for (int i = blockIdx.x * 256 + threadIdx.x; i < n4; i += 32 * 256) {
        float4 L = p4[i], Tt = t4[i], SP = sp4[i], SL = sl4[i];
        float p;
        p = sigm(L.x); v[0] += SP.x * Tt.x; v[1] += SP.x; v[2] += SL.x * p; v[3] += SL.x; v[4] += p * Tt.x; v[5] += p; v[6] += Tt.x;
        p = sigm(L.y); v[0] += SP.y * Tt.y; v[1] += SP.y; v[2] += SL.y * p; v[3] += SL.y; v[4] += p * Tt.y; v[5] += p; v[6] += Tt.y;
        p = sigm(L.z); v[0] += SP.z * Tt.z; v[1] += SP.z; v[2] += SL.z * p; v[3] += SL.z; v[4] += p * Tt.z; v[5] += p; v[6] += Tt.z;
        p = sigm(L.w); v[0] += SP.w * Tt.w; v[1] += SP.w; v[2] += SL.w * p; v[3] += SL.w; v[4] += p * Tt.w; v[5] += p; v[6] += Tt.w;
    }
    #pragma unroll
    for (int off = 32; off > 0; off >>= 1)
        #pragma unroll
        for (int q = 0; q < 7; ++q) v[q] += __shfl_down(v[q], off);
    __shared__ float wred[4][7];
    int lane = threadIdx.x & 63, w = threadIdx.x >> 6;
    if (lane == 0)
        #pragma unroll
        for (int q = 0; q < 7; ++q) wred[w][q] = v[q];
    __syncthreads();
    if (threadIdx.x == 0) {
        #pragma unroll
        for (int q = 0; q < 7; ++q)
            partial[(sample * 32 + blockIdx.x) * 7 + q] =
                wred[0][q] + wred[1][q] + wred[2][q] + wred[3][q];
    }
}

__global__ __launch_bounds__(256) void final_kernel(const float* __restrict__ partial,
                                                    float* __restrict__ out)
{
    const int t = threadIdx.x;
    const int sample = t >> 5, part = t & 31;
    float v[7];
    #pragma unroll
    for (int q = 0; q < 7; ++q) v[q] = partial[(sample * 32 + part) * 7 + q];
    #pragma unroll
    for (int off = 16; off > 0; off >>= 1)
        #pragma unroll
        for (int q = 0; q < 7; ++q) v[q] += __shfl_down(v[q], off, 32);
    __shared__ float acc[NSAMP][7];
    if (part == 0)
        #pragma unroll
        for (int q = 0; q < 7; ++q) acc[sample][q] = v[q];
    __syncthreads();
    if (t == 0) {
        float cl = 0.f, dice = 0.f;
        for (int n = 0; n < NSAMP; n++) {
            float A = acc[n][0], Bv = acc[n][1], Cc = acc[n][2], D = acc[n][3];
            float E = acc[n][4], F = acc[n][5], G = acc[n][6];
            float tprec = (A + 1.0f) / (Bv + 1.0f);
            float tsens = (Cc + 1.0f) / (D + 1.0f);
            cl   += 1.0f - 2.0f * tprec * tsens / (tprec + tsens);
            dice += 1.0f - 2.0f * (E + 1.0f) / (F + G + 1.0f);
        }
        out[0] = 0.7f * (dice / NSAMP) + 0.3f * (cl / NSAMP);
    }
}

extern "C" void kernel_launch(void* const* d_in, const int* in_sizes, int n_in,
                              void* d_out, int out_size, void* d_ws, size_t ws_size,
                              hipStream_t stream)
{
    const float* logits = (const float*)d_in[0];
    const float* target = (const float*)d_in[1];
    float* out = (float*)d_out;

    const size_t NTOT = (size_t)NIMG * PS;
    float* Xa = (float*)d_ws;                       // Xa | Xb | S | partial
    float* Xb = Xa + NTOT;
    float* S  = Xb + NTOT;
    float* partial = S + NTOT;                      // 256*7 floats

    const int n4 = (NSAMP * PS) / 4;
    prep_kernel<<<n4 / 256, 256, 0, stream>>>((const float4*)logits, (const float4*)target,
                                              (float4*)Xa, n4);

    // 51 levels = 6 + 9*5.  blocks = NSTRIP*NBANDS*NIMG/4.
    fused_pipe<6, true ><<<11 * 64, 256, 0, stream>>>(Xa, Xb, S);   // 2816 waves
    fused_pipe<5, false><<<10 * 64, 256, 0, stream>>>(Xb, Xa, S);   // 2560 waves
    fused_pipe<5, false><<<10 * 64, 256, 0, stream>>>(Xa, Xb, S);
    fused_pipe<5, false><<<10 * 64, 256, 0, stream>>>(Xb, Xa, S);
    fused_pipe<5, false><<<10 * 64, 256, 0, stream>>>(Xa, Xb, S);
    fused_pipe<5, false><<<10 * 64, 256, 0, stream>>>(Xb, Xa, S);
    fused_pipe<5, false><<<10 * 64, 256, 0, stream>>>(Xa, Xb, S);
    fused_pipe<5, false><<<10 * 64, 256, 0, stream>>>(Xb, Xa, S);
    fused_pipe<5, false><<<10 * 64, 256, 0, stream>>>(Xa, Xb, S);
    fused_pipe<5, false><<<10 * 64, 256, 0, stream>>>(Xb, Xa, S);

    reduce_kernel<<<dim3(32, NSAMP), 256, 0, stream>>>(logits, target, S, partial);
    final_kernel<<<1, 256, 0, stream>>>(partial, out);
}